// Round 7
// baseline (363.297 us; speedup 1.0000x reference)
//
#include <hip/hip_runtime.h>
#include <math.h>
#include <stdint.h>

// Problem constants (B=2, T=2048, C=1024, H=16, hs=64)
#define B_  2
#define T_  2048
#define C_  1024
#define H_  16
#define HS_ 64
#define M_  4096

typedef unsigned short u16;
typedef u16   u16x4 __attribute__((ext_vector_type(4)));
typedef u16   u16x8 __attribute__((ext_vector_type(8)));
typedef float f32x4 __attribute__((ext_vector_type(4)));

typedef uint32_t __attribute__((address_space(1))) u32_as1;
typedef uint32_t __attribute__((address_space(3))) u32_as3;

// fp32 -> bf16 round-to-nearest-even
__device__ __forceinline__ u16 f2bf(float f) {
    uint32_t u = __float_as_uint(f);
    u = (u + 0x7fffu + ((u >> 16) & 1u)) >> 16;
    return (u16)u;
}

// async global->LDS, 16 B per lane (dest = wave-uniform base + lane*16)
__device__ __forceinline__ void gload_lds16(const void* g, void* l) {
    __builtin_amdgcn_global_load_lds((const u32_as1*)g, (u32_as3*)l, 16, 0, 0);
}

// D = A(16x32) * B(32x16) + C
__device__ __forceinline__ f32x4 mfma_bf16(u16x8 a, u16x8 b, f32x4 c) {
    asm("v_mfma_f32_16x16x32_bf16 %0, %1, %2, %0" : "+v"(c) : "v"(a), "v"(b));
    return c;
}

// ---------------------------------------------------------------------------
// Prep kernels
// ---------------------------------------------------------------------------
__global__ __launch_bounds__(256)
void cast_f32_bf16(const float* __restrict__ x, u16* __restrict__ xb) {
    const int i = blockIdx.x * 256 + threadIdx.x;
    const float4* xi = (const float4*)x;
    float4 a = xi[2 * i], b = xi[2 * i + 1];
    u16x8 o;
    o[0] = f2bf(a.x); o[1] = f2bf(a.y); o[2] = f2bf(a.z); o[3] = f2bf(a.w);
    o[4] = f2bf(b.x); o[5] = f2bf(b.y); o[6] = f2bf(b.z); o[7] = f2bf(b.w);
    *(u16x8*)&xb[(size_t)i * 8] = o;
}

__global__ __launch_bounds__(256)
void transpose_cast(const float* __restrict__ W, u16* __restrict__ Wt, int K, int N) {
    __shared__ float tile[64][65];
    const int n0 = blockIdx.x * 64, k0 = blockIdx.y * 64;
    const int tid = threadIdx.x;
    #pragma unroll
    for (int p = 0; p < 16; ++p) {
        int idx = p * 256 + tid;
        int r = idx >> 6, c = idx & 63;
        tile[r][c] = W[(size_t)(k0 + r) * N + n0 + c];
    }
    __syncthreads();
    #pragma unroll
    for (int p = 0; p < 16; ++p) {
        int idx = p * 256 + tid;
        int r = idx >> 6, c = idx & 63;
        Wt[(size_t)(n0 + r) * K + k0 + c] = f2bf(tile[c][r]);
    }
}

__global__ __launch_bounds__(256)
void transpose4_cast(const float* __restrict__ A0, const float* __restrict__ A1,
                     const float* __restrict__ A2, const float* __restrict__ A3,
                     u16* __restrict__ Wt) {
    __shared__ float tile[64][65];
    const float* src = (blockIdx.z == 0) ? A0 : (blockIdx.z == 1) ? A1
                     : (blockIdx.z == 2) ? A2 : A3;
    u16* dst = Wt + (size_t)blockIdx.z * 1048576;
    const int n0 = blockIdx.x * 64, k0 = blockIdx.y * 64;
    const int tid = threadIdx.x;
    #pragma unroll
    for (int p = 0; p < 16; ++p) {
        int idx = p * 256 + tid;
        int r = idx >> 6, c = idx & 63;
        tile[r][c] = src[(size_t)(k0 + r) * 1024 + n0 + c];
    }
    __syncthreads();
    #pragma unroll
    for (int p = 0; p < 16; ++p) {
        int idx = p * 256 + tid;
        int r = idx >> 6, c = idx & 63;
        dst[(size_t)(n0 + r) * 1024 + k0 + c] = f2bf(tile[c][r]);
    }
}

// ---------------------------------------------------------------------------
// bf16 MFMA GEMM: Y = A[M,K] @ Bt[N,K]^T, 128x128 tile, BK=64, 256 threads.
// DBUF: double-buffered LDS + prefetch (for grid=256 dispatches with 1
// block/CU where no cross-block wave overlap exists to hide HBM latency).
// EP_QKV scatters q,k -> [B,H,T,64] and v -> [B,H,64,T] (transposed, packed).
// ---------------------------------------------------------------------------
enum { EP_QKV = 0, EP_PROJ = 1, EP_RELU = 2, EP_RESID = 3 };

template<int EP, bool DBUF>
__global__ __launch_bounds__(256)
void gemm_bf16(const u16* __restrict__ A, const u16* __restrict__ Bt,
               const float* __restrict__ bias, const float* __restrict__ resid,
               float* __restrict__ fout, u16* __restrict__ bout,
               int N, int K) {
    __shared__ __align__(16) u16 Al[(DBUF ? 2 : 1) * 128 * 64];
    __shared__ __align__(16) u16 Bl[(DBUF ? 2 : 1) * 128 * 64];
    const int tid  = threadIdx.x;
    const int lane = tid & 63, w = tid >> 6;
    const int wr = w >> 1, wc = w & 1;
    const int brow = blockIdx.y * 128, bcol = blockIdx.x * 128;
    const int rg   = lane >> 3;
    const int csrc = (lane & 7) ^ rg;

    auto stageg = [&](int k0, int buf) {
        #pragma unroll
        for (int i = 0; i < 4; ++i) {
            const int seg = i * 4 + w;      // 0..15, wave-uniform
            gload_lds16(A  + (size_t)(brow + seg * 8 + rg) * K + k0 + csrc * 8,
                        &Al[buf * 8192 + seg * 512]);
            gload_lds16(Bt + (size_t)(bcol + seg * 8 + rg) * K + k0 + csrc * 8,
                        &Bl[buf * 8192 + seg * 512]);
        }
    };

    f32x4 acc[4][4];
    #pragma unroll
    for (int i = 0; i < 4; ++i)
        #pragma unroll
        for (int j = 0; j < 4; ++j)
            acc[i][j] = f32x4{0.f, 0.f, 0.f, 0.f};

    if (DBUF) stageg(0, 0);
    int cur = 0;
    for (int k0 = 0; k0 < K; k0 += 64) {
        if (DBUF) {
            __syncthreads();                 // buf[cur] loads done; prev compute done
            if (k0 + 64 < K) stageg(k0 + 64, cur ^ 1);
        } else {
            stageg(k0, 0);
            __syncthreads();
        }
        const u16* Ab = &Al[cur * 8192];
        const u16* Bb = &Bl[cur * 8192];
        #pragma unroll
        for (int kk = 0; kk < 2; ++kk) {
            u16x8 af[4], bfv[4];
            #pragma unroll
            for (int mi = 0; mi < 4; ++mi) {
                const int row = wr * 64 + mi * 16 + (lane & 15);
                const int ch  = (kk * 4 + (lane >> 4)) ^ (row & 7);
                af[mi] = *(const u16x8*)&Ab[row * 64 + ch * 8];
            }
            #pragma unroll
            for (int nj = 0; nj < 4; ++nj) {
                const int row = wc * 64 + nj * 16 + (lane & 15);
                const int ch  = (kk * 4 + (lane >> 4)) ^ (row & 7);
                bfv[nj] = *(const u16x8*)&Bb[row * 64 + ch * 8];
            }
            #pragma unroll
            for (int mi = 0; mi < 4; ++mi)
                #pragma unroll
                for (int nj = 0; nj < 4; ++nj)
                    acc[mi][nj] = mfma_bf16(af[mi], bfv[nj], acc[mi][nj]);
        }
        if (DBUF) cur ^= 1;
        else __syncthreads();
    }

    // Epilogue. D layout: col = lane&15, row = (lane>>4)*4 + r
    const int g = lane >> 4, c16 = lane & 15;
    #pragma unroll
    for (int mi = 0; mi < 4; ++mi) {
        #pragma unroll
        for (int nj = 0; nj < 4; ++nj) {
            if (EP == EP_QKV) {
                const int col = bcol + wc * 64 + nj * 16 + c16;
                const int region = col >> 10, c = col & 1023;
                const int hh = c >> 6, d = c & 63;
                const int row0 = brow + wr * 64 + mi * 16 + g * 4;
                const int bb = row0 >> 11, t0 = row0 & 2047;
                if (region < 2) {   // q,k: [B,H,T,64]
                    #pragma unroll
                    for (int r = 0; r < 4; ++r)
                        bout[(size_t)region * 4194304 +
                             (((size_t)(bb * 16 + hh)) * 2048 + t0 + r) * 64 + d] =
                            f2bf(acc[mi][nj][r]);
                } else {            // v: [B,H,64,T] transposed, packed 8B
                    u16x4 pk;
                    #pragma unroll
                    for (int r = 0; r < 4; ++r) pk[r] = f2bf(acc[mi][nj][r]);
                    *(u16x4*)&bout[(size_t)2 * 4194304 +
                                   (((size_t)(bb * 16 + hh)) * 64 + d) * 2048 + t0] = pk;
                }
            } else {
                #pragma unroll
                for (int r = 0; r < 4; ++r) {
                    const int row = brow + wr * 64 + mi * 16 + g * 4 + r;
                    const int col = bcol + wc * 64 + nj * 16 + c16;
                    const float vacc = acc[mi][nj][r];
                    if (EP == EP_PROJ) {
                        const float o = vacc + bias[col] + resid[(size_t)row * N + col];
                        fout[(size_t)row * N + col] = o;
                        bout[(size_t)row * N + col] = f2bf(o);
                    } else if (EP == EP_RELU) {
                        float o = vacc + bias[col];
                        o = fmaxf(o, 0.f);
                        bout[(size_t)row * N + col] = f2bf(o);
                    } else { // EP_RESID
                        const float o = vacc + bias[col] + fout[(size_t)row * N + col];
                        fout[(size_t)row * N + col] = o;
                    }
                }
            }
        }
    }
}

// ---------------------------------------------------------------------------
// bf16 MFMA flash attention (causal), load-balanced + XCD-L2-aware:
// flat 512-block grid; XCD x (= lin&7 by round-robin dispatch) owns 4 (b,h)
// groups -> per-XCD K/V working set 2 MB < 4 MB L2. Block handles q-tiles
// {pair, 31-pair} = constant 33 kv-tiles. K/V double-buffered in LDS with
// prefetch (stage kv+1 before computing kv) to hide HBM latency at the
// grid-limited 2-blocks/CU occupancy. V pre-transposed globally [B,H,64,T].
// ---------------------------------------------------------------------------
__global__ __launch_bounds__(256)
void attn_mfma(const u16* __restrict__ q, const u16* __restrict__ k,
               const u16* __restrict__ vt, u16* __restrict__ o) {
    __shared__ __align__(16) u16 Kl[2][64 * 64];
    __shared__ __align__(16) u16 Vl[2][64 * 64];
    __shared__ __align__(16) u16 Pl[4 * 16 * 72];
    const int tid = threadIdx.x, lane = tid & 63, w = tid >> 6;
    const int g = lane >> 4, c16 = lane & 15;
    const int rg = lane >> 3, csrc = (lane & 7) ^ rg;

    // XCD-aware decode: consecutive lin -> consecutive XCD (round-robin), so
    // give XCD x the groups 4x..4x+3; all 16 pair-blocks of a group share K/V.
    const int lin  = blockIdx.x;            // 0..511
    const int xcd  = lin & 7, sub = lin >> 3;
    const int grp  = xcd * 4 + (sub >> 4);  // 0..31 = (b,h)
    const int pair = sub & 15;
    const int h = grp & 15, b = grp >> 4;
    const float scale = 0.03125f;  // 1024^-0.5

    const size_t hb  = ((size_t)b * H_ + h) * T_ * HS_;   // q,k: [B,H,T,64]
    const u16* qh = q  + hb;
    const u16* kh = k  + hb;
    const u16* vh = vt + hb;                              // v: [B,H,64,T]

    auto stage = [&](int kv, int buf) {
        #pragma unroll
        for (int i = 0; i < 2; ++i) {
            const int seg = i * 4 + w;   // 0..7, wave-uniform
            gload_lds16(kh + (size_t)(kv * 64 + seg * 8 + rg) * 64 + csrc * 8,
                        &Kl[buf][seg * 512]);
            gload_lds16(vh + (size_t)(seg * 8 + rg) * T_ + kv * 64 + csrc * 8,
                        &Vl[buf][seg * 512]);
        }
    };

    int cur = 0;
    #pragma unroll
    for (int phase = 0; phase < 2; ++phase) {
        const int qt = phase ? (31 - pair) : pair;

        // Q fragments (A-frag: row = lane&15, k = g*8+reg)
        const size_t qrow_l = (size_t)(qt * 64 + w * 16 + c16);
        u16x8 qf[2];
        qf[0] = *(const u16x8*)&qh[qrow_l * 64 + g * 8];
        qf[1] = *(const u16x8*)&qh[qrow_l * 64 + 32 + g * 8];

        float m_run[4], l_run[4];
        f32x4 oacc[4];
        #pragma unroll
        for (int r = 0; r < 4; ++r) { m_run[r] = -INFINITY; l_run[r] = 0.f; }
        #pragma unroll
        for (int nt = 0; nt < 4; ++nt) oacc[nt] = f32x4{0.f, 0.f, 0.f, 0.f};

        __syncthreads();          // all waves done with prior phase's buffers
        stage(0, cur);            // prologue stage

        for (int kv = 0; kv <= qt; ++kv) {
            __syncthreads();      // tile kv ready (drains vmcnt); prev compute done
            if (kv < qt) stage(kv + 1, cur ^ 1);   // prefetch hides under compute

            // S = Q K^T  (4 key-tiles of 16)
            f32x4 s[4];
            #pragma unroll
            for (int kt = 0; kt < 4; ++kt) s[kt] = f32x4{0.f, 0.f, 0.f, 0.f};
            __builtin_amdgcn_s_setprio(1);
            #pragma unroll
            for (int kt = 0; kt < 4; ++kt)
                #pragma unroll
                for (int kk = 0; kk < 2; ++kk) {
                    const int row = kt * 16 + c16;
                    const int ch  = (kk * 4 + g) ^ (row & 7);
                    u16x8 kf = *(const u16x8*)&Kl[cur][row * 64 + ch * 8];
                    s[kt] = mfma_bf16(qf[kk], kf, s[kt]);
                }
            __builtin_amdgcn_s_setprio(0);

            // scale + causal mask (only diagonal tile)
            const bool last = (kv == qt);
            float sv[4][4];
            #pragma unroll
            for (int kt = 0; kt < 4; ++kt)
                #pragma unroll
                for (int r = 0; r < 4; ++r) {
                    float val = s[kt][r] * scale;
                    if (last && (kv * 64 + kt * 16 + c16) > (qt * 64 + w * 16 + g * 4 + r))
                        val = -INFINITY;
                    sv[kt][r] = val;
                }

            // row max across the 16 lanes holding each row
            float pm[4];
            #pragma unroll
            for (int r = 0; r < 4; ++r)
                pm[r] = fmaxf(fmaxf(sv[0][r], sv[1][r]), fmaxf(sv[2][r], sv[3][r]));
            #pragma unroll
            for (int mask = 1; mask < 16; mask <<= 1)
                #pragma unroll
                for (int r = 0; r < 4; ++r)
                    pm[r] = fmaxf(pm[r], __shfl_xor(pm[r], mask));

            float corr[4];
            #pragma unroll
            for (int r = 0; r < 4; ++r) {
                const float nm = fmaxf(m_run[r], pm[r]);
                corr[r] = __expf(m_run[r] - nm);   // 0 on first tile
                m_run[r] = nm;
            }

            float rs[4] = {0.f, 0.f, 0.f, 0.f};
            float ps[4][4];
            #pragma unroll
            for (int kt = 0; kt < 4; ++kt)
                #pragma unroll
                for (int r = 0; r < 4; ++r) {
                    const float p = __expf(sv[kt][r] - m_run[r]);
                    ps[kt][r] = p;
                    rs[r] += p;
                }
            #pragma unroll
            for (int mask = 1; mask < 16; mask <<= 1)
                #pragma unroll
                for (int r = 0; r < 4; ++r)
                    rs[r] += __shfl_xor(rs[r], mask);
            #pragma unroll
            for (int r = 0; r < 4; ++r) l_run[r] = l_run[r] * corr[r] + rs[r];
            #pragma unroll
            for (int nt = 0; nt < 4; ++nt)
                #pragma unroll
                for (int r = 0; r < 4; ++r) oacc[nt][r] *= corr[r];

            #pragma unroll
            for (int kt = 0; kt < 4; ++kt)
                #pragma unroll
                for (int r = 0; r < 4; ++r)
                    Pl[w * 1152 + (g * 4 + r) * 72 + kt * 16 + c16] = f2bf(ps[kt][r]);

            // O += P V
            __builtin_amdgcn_s_setprio(1);
            #pragma unroll
            for (int kkp = 0; kkp < 2; ++kkp) {
                u16x8 pf = *(const u16x8*)&Pl[w * 1152 + c16 * 72 + kkp * 32 + g * 8];
                #pragma unroll
                for (int nt = 0; nt < 4; ++nt) {
                    const int row = nt * 16 + c16;          // d
                    const int ch  = (kkp * 4 + g) ^ (row & 7);
                    u16x8 vf = *(const u16x8*)&Vl[cur][row * 64 + ch * 8];
                    oacc[nt] = mfma_bf16(pf, vf, oacc[nt]);
                }
            }
            __builtin_amdgcn_s_setprio(0);
            cur ^= 1;
        }

        // epilogue: o[b, t, h*64+d] bf16 in [M, C] layout
        float inv[4];
        #pragma unroll
        for (int r = 0; r < 4; ++r) inv[r] = 1.f / l_run[r];
        const int orow = qt * 64 + w * 16;
        #pragma unroll
        for (int nt = 0; nt < 4; ++nt)
            #pragma unroll
            for (int r = 0; r < 4; ++r)
                o[((size_t)(b * T_ + orow + g * 4 + r)) * C_ + h * 64 + nt * 16 + c16] =
                    f2bf(oacc[nt][r] * inv[r]);
    }
}

// ---------------------------------------------------------------------------
// Orchestration. ws layout (u16 elems, 64 MiB total):
//   [0)        Wqkvt  [3072][1024]          3,145,728
//   [3145728)  Wpt    [1024][1024]          1,048,576
//   [4194304)  W1t    [4096][1024]          4,194,304
//   [8388608)  W2t    [1024][4096]          4,194,304
//   [12582912) xb     [4096][1024]          4,194,304   (reused as x1b)
//   [16777216) q/k/vt 3x[B,H,..]           12,582,912   (reused as h1b)
//   [29360128) ab     [4096][1024]          4,194,304
// ---------------------------------------------------------------------------
extern "C" void kernel_launch(void* const* d_in, const int* in_sizes, int n_in,
                              void* d_out, int out_size, void* d_ws, size_t ws_size,
                              hipStream_t stream) {
    const float* x     = (const float*)d_in[0];
    const float* Wq    = (const float*)d_in[1];
    const float* Wk    = (const float*)d_in[2];
    const float* Wv    = (const float*)d_in[3];
    const float* Wproj = (const float*)d_in[4];
    const float* bproj = (const float*)d_in[5];
    const float* W1    = (const float*)d_in[6];
    const float* b1    = (const float*)d_in[7];
    const float* W2    = (const float*)d_in[8];
    const float* b2    = (const float*)d_in[9];
    float* out = (float*)d_out;

    u16* ws    = (u16*)d_ws;
    u16* Wqkvt = ws;
    u16* Wpt   = ws + 3145728;
    u16* W1t   = ws + 4194304;
    u16* W2t   = ws + 8388608;
    u16* xb    = ws + 12582912;
    u16* qb    = ws + 16777216;
    u16* ab    = ws + 29360128;
    u16* x1b   = xb;   // xb dead after QKV gemm
    u16* h1b   = qb;   // q/k/v + ab dead after proj gemm

    dim3 blk(256);

    cast_f32_bf16<<<dim3(2048), blk, 0, stream>>>(x, xb);
    transpose4_cast<<<dim3(16, 16, 4), blk, 0, stream>>>(Wq, Wk, Wv, Wproj, Wqkvt);
    transpose_cast<<<dim3(64, 16), blk, 0, stream>>>(W1, W1t, 1024, 4096);
    transpose_cast<<<dim3(16, 64), blk, 0, stream>>>(W2, W2t, 4096, 1024);

    // q/k -> [B,H,T,64], v -> [B,H,64,T] (transposed)
    gemm_bf16<EP_QKV, false><<<dim3(24, 32), blk, 0, stream>>>(
        xb, Wqkvt, nullptr, nullptr, nullptr, qb, 3072, 1024);

    // causal flash attention (load-balanced pairs, XCD-aware) -> ab [M,C] bf16
    attn_mfma<<<dim3(512), blk, 0, stream>>>(
        qb, qb + 4194304, qb + 8388608, ab);

    // x1 = x + attn @ Wproj + bproj   (grid=256 -> DBUF prefetch)
    gemm_bf16<EP_PROJ, true><<<dim3(8, 32), blk, 0, stream>>>(
        ab, Wpt, bproj, x, out, x1b, 1024, 1024);

    // h1 = relu(x1 @ W1 + b1)
    gemm_bf16<EP_RELU, false><<<dim3(32, 32), blk, 0, stream>>>(
        x1b, W1t, b1, nullptr, nullptr, h1b, 4096, 1024);

    // out = x1 + h1 @ W2 + b2         (grid=256 -> DBUF prefetch)
    gemm_bf16<EP_RESID, true><<<dim3(8, 32), blk, 0, stream>>>(
        h1b, W2t, b2, nullptr, out, nullptr, 1024, 4096);
}

// Round 8
// 344.414 us; speedup vs baseline: 1.0548x; 1.0548x over previous
//
#include <hip/hip_runtime.h>
#include <math.h>
#include <stdint.h>

// Problem constants (B=2, T=2048, C=1024, H=16, hs=64)
#define B_  2
#define T_  2048
#define C_  1024
#define H_  16
#define HS_ 64
#define M_  4096

typedef unsigned short u16;
typedef u16   u16x4 __attribute__((ext_vector_type(4)));
typedef u16   u16x8 __attribute__((ext_vector_type(8)));
typedef float f32x4 __attribute__((ext_vector_type(4)));

typedef uint32_t __attribute__((address_space(1))) u32_as1;
typedef uint32_t __attribute__((address_space(3))) u32_as3;

// fp32 -> bf16 round-to-nearest-even
__device__ __forceinline__ u16 f2bf(float f) {
    uint32_t u = __float_as_uint(f);
    u = (u + 0x7fffu + ((u >> 16) & 1u)) >> 16;
    return (u16)u;
}

// async global->LDS, 16 B per lane (dest = wave-uniform base + lane*16)
__device__ __forceinline__ void gload_lds16(const void* g, void* l) {
    __builtin_amdgcn_global_load_lds((const u32_as1*)g, (u32_as3*)l, 16, 0, 0);
}

// D = A(16x32) * B(32x16) + C
__device__ __forceinline__ f32x4 mfma_bf16(u16x8 a, u16x8 b, f32x4 c) {
    asm("v_mfma_f32_16x16x32_bf16 %0, %1, %2, %0" : "+v"(c) : "v"(a), "v"(b));
    return c;
}

// ---------------------------------------------------------------------------
// Prep kernels
// ---------------------------------------------------------------------------
__global__ __launch_bounds__(256)
void cast_f32_bf16(const float* __restrict__ x, u16* __restrict__ xb) {
    const int i = blockIdx.x * 256 + threadIdx.x;
    const float4* xi = (const float4*)x;
    float4 a = xi[2 * i], b = xi[2 * i + 1];
    u16x8 o;
    o[0] = f2bf(a.x); o[1] = f2bf(a.y); o[2] = f2bf(a.z); o[3] = f2bf(a.w);
    o[4] = f2bf(b.x); o[5] = f2bf(b.y); o[6] = f2bf(b.z); o[7] = f2bf(b.w);
    *(u16x8*)&xb[(size_t)i * 8] = o;
}

__global__ __launch_bounds__(256)
void transpose_cast(const float* __restrict__ W, u16* __restrict__ Wt, int K, int N) {
    __shared__ float tile[64][65];
    const int n0 = blockIdx.x * 64, k0 = blockIdx.y * 64;
    const int tid = threadIdx.x;
    #pragma unroll
    for (int p = 0; p < 16; ++p) {
        int idx = p * 256 + tid;
        int r = idx >> 6, c = idx & 63;
        tile[r][c] = W[(size_t)(k0 + r) * N + n0 + c];
    }
    __syncthreads();
    #pragma unroll
    for (int p = 0; p < 16; ++p) {
        int idx = p * 256 + tid;
        int r = idx >> 6, c = idx & 63;
        Wt[(size_t)(n0 + r) * K + k0 + c] = f2bf(tile[c][r]);
    }
}

__global__ __launch_bounds__(256)
void transpose4_cast(const float* __restrict__ A0, const float* __restrict__ A1,
                     const float* __restrict__ A2, const float* __restrict__ A3,
                     u16* __restrict__ Wt) {
    __shared__ float tile[64][65];
    const float* src = (blockIdx.z == 0) ? A0 : (blockIdx.z == 1) ? A1
                     : (blockIdx.z == 2) ? A2 : A3;
    u16* dst = Wt + (size_t)blockIdx.z * 1048576;
    const int n0 = blockIdx.x * 64, k0 = blockIdx.y * 64;
    const int tid = threadIdx.x;
    #pragma unroll
    for (int p = 0; p < 16; ++p) {
        int idx = p * 256 + tid;
        int r = idx >> 6, c = idx & 63;
        tile[r][c] = src[(size_t)(k0 + r) * 1024 + n0 + c];
    }
    __syncthreads();
    #pragma unroll
    for (int p = 0; p < 16; ++p) {
        int idx = p * 256 + tid;
        int r = idx >> 6, c = idx & 63;
        dst[(size_t)(n0 + r) * 1024 + k0 + c] = f2bf(tile[c][r]);
    }
}

// ---------------------------------------------------------------------------
// bf16 MFMA GEMM: Y = A[M,K] @ Bt[N,K]^T, 128xBN tile, BK=64, 256 threads.
// BN=128: 4 waves in 2x2, wave-tile 64x64 (acc 4x4).
// BN=64:  4 waves in 2x2, wave-tile 64x32 (acc 4x2) -> grid doubles, for
//         N=1024 dispatches that otherwise run at 1 block/CU (latency-bound).
// DBUF: double-buffered LDS + prefetch.
// EP_QKV scatters q,k -> [B,H,T,64] and v -> [B,H,64,T] (transposed, packed).
// ---------------------------------------------------------------------------
enum { EP_QKV = 0, EP_PROJ = 1, EP_RELU = 2, EP_RESID = 3 };

template<int EP, bool DBUF, int BN>
__global__ __launch_bounds__(256)
void gemm_bf16(const u16* __restrict__ A, const u16* __restrict__ Bt,
               const float* __restrict__ bias, const float* __restrict__ resid,
               float* __restrict__ fout, u16* __restrict__ bout,
               int N, int K) {
    constexpr int WN = BN / 2;        // wave N-tile
    constexpr int NJ = WN / 16;       // N-frags per wave
    constexpr int ABUF = 128 * 64;    // elems per A buffer
    constexpr int BBUF = BN * 64;     // elems per B buffer
    __shared__ __align__(16) u16 Al[(DBUF ? 2 : 1) * ABUF];
    __shared__ __align__(16) u16 Bl[(DBUF ? 2 : 1) * BBUF];
    const int tid  = threadIdx.x;
    const int lane = tid & 63, w = tid >> 6;
    const int wr = w >> 1, wc = w & 1;
    const int brow = blockIdx.y * 128, bcol = blockIdx.x * BN;
    const int rg   = lane >> 3;
    const int csrc = (lane & 7) ^ rg;

    auto stageg = [&](int k0, int buf) {
        #pragma unroll
        for (int i = 0; i < 4; ++i) {
            const int seg = i * 4 + w;      // 0..15, wave-uniform
            gload_lds16(A + (size_t)(brow + seg * 8 + rg) * K + k0 + csrc * 8,
                        &Al[buf * ABUF + seg * 512]);
        }
        #pragma unroll
        for (int i = 0; i < BN / 32; ++i) {
            const int seg = i * 4 + w;      // 0..BN/8-1, wave-uniform
            gload_lds16(Bt + (size_t)(bcol + seg * 8 + rg) * K + k0 + csrc * 8,
                        &Bl[buf * BBUF + seg * 512]);
        }
    };

    f32x4 acc[4][NJ];
    #pragma unroll
    for (int i = 0; i < 4; ++i)
        #pragma unroll
        for (int j = 0; j < NJ; ++j)
            acc[i][j] = f32x4{0.f, 0.f, 0.f, 0.f};

    if (DBUF) stageg(0, 0);
    int cur = 0;
    for (int k0 = 0; k0 < K; k0 += 64) {
        if (DBUF) {
            __syncthreads();                 // buf[cur] loads done; prev compute done
            if (k0 + 64 < K) stageg(k0 + 64, cur ^ 1);
        } else {
            stageg(k0, 0);
            __syncthreads();
        }
        const u16* Ab = &Al[cur * ABUF];
        const u16* Bb = &Bl[cur * BBUF];
        #pragma unroll
        for (int kk = 0; kk < 2; ++kk) {
            u16x8 af[4], bfv[NJ];
            #pragma unroll
            for (int mi = 0; mi < 4; ++mi) {
                const int row = wr * 64 + mi * 16 + (lane & 15);
                const int ch  = (kk * 4 + (lane >> 4)) ^ (row & 7);
                af[mi] = *(const u16x8*)&Ab[row * 64 + ch * 8];
            }
            #pragma unroll
            for (int nj = 0; nj < NJ; ++nj) {
                const int row = wc * WN + nj * 16 + (lane & 15);
                const int ch  = (kk * 4 + (lane >> 4)) ^ (row & 7);
                bfv[nj] = *(const u16x8*)&Bb[row * 64 + ch * 8];
            }
            #pragma unroll
            for (int mi = 0; mi < 4; ++mi)
                #pragma unroll
                for (int nj = 0; nj < NJ; ++nj)
                    acc[mi][nj] = mfma_bf16(af[mi], bfv[nj], acc[mi][nj]);
        }
        if (DBUF) cur ^= 1;
        else __syncthreads();
    }

    // Epilogue. D layout: col = lane&15, row = (lane>>4)*4 + r
    const int g = lane >> 4, c16 = lane & 15;
    #pragma unroll
    for (int mi = 0; mi < 4; ++mi) {
        #pragma unroll
        for (int nj = 0; nj < NJ; ++nj) {
            if (EP == EP_QKV) {
                const int col = bcol + wc * WN + nj * 16 + c16;
                const int region = col >> 10, c = col & 1023;
                const int hh = c >> 6, d = c & 63;
                const int row0 = brow + wr * 64 + mi * 16 + g * 4;
                const int bb = row0 >> 11, t0 = row0 & 2047;
                if (region < 2) {   // q,k: [B,H,T,64]
                    #pragma unroll
                    for (int r = 0; r < 4; ++r)
                        bout[(size_t)region * 4194304 +
                             (((size_t)(bb * 16 + hh)) * 2048 + t0 + r) * 64 + d] =
                            f2bf(acc[mi][nj][r]);
                } else {            // v: [B,H,64,T] transposed, packed 8B
                    u16x4 pk;
                    #pragma unroll
                    for (int r = 0; r < 4; ++r) pk[r] = f2bf(acc[mi][nj][r]);
                    *(u16x4*)&bout[(size_t)2 * 4194304 +
                                   (((size_t)(bb * 16 + hh)) * 64 + d) * 2048 + t0] = pk;
                }
            } else {
                #pragma unroll
                for (int r = 0; r < 4; ++r) {
                    const int row = brow + wr * 64 + mi * 16 + g * 4 + r;
                    const int col = bcol + wc * WN + nj * 16 + c16;
                    const float vacc = acc[mi][nj][r];
                    if (EP == EP_PROJ) {
                        const float o = vacc + bias[col] + resid[(size_t)row * N + col];
                        fout[(size_t)row * N + col] = o;
                        bout[(size_t)row * N + col] = f2bf(o);
                    } else if (EP == EP_RELU) {
                        float o = vacc + bias[col];
                        o = fmaxf(o, 0.f);
                        bout[(size_t)row * N + col] = f2bf(o);
                    } else { // EP_RESID
                        const float o = vacc + bias[col] + fout[(size_t)row * N + col];
                        fout[(size_t)row * N + col] = o;
                    }
                }
            }
        }
    }
}

// ---------------------------------------------------------------------------
// bf16 MFMA flash attention (causal), load-balanced + XCD-L2-aware:
// flat 512-block grid; XCD x (= lin&7 by round-robin dispatch) owns 4 (b,h)
// groups -> per-XCD K/V working set 2 MB < 4 MB L2. Block handles q-tiles
// {pair, 31-pair} = constant 33 kv-tiles. K/V double-buffered in LDS with
// prefetch (stage kv+1 before computing kv) to hide HBM latency at the
// grid-limited 2-blocks/CU occupancy. V pre-transposed globally [B,H,64,T].
// ---------------------------------------------------------------------------
__global__ __launch_bounds__(256)
void attn_mfma(const u16* __restrict__ q, const u16* __restrict__ k,
               const u16* __restrict__ vt, u16* __restrict__ o) {
    __shared__ __align__(16) u16 Kl[2][64 * 64];
    __shared__ __align__(16) u16 Vl[2][64 * 64];
    __shared__ __align__(16) u16 Pl[4 * 16 * 72];
    const int tid = threadIdx.x, lane = tid & 63, w = tid >> 6;
    const int g = lane >> 4, c16 = lane & 15;
    const int rg = lane >> 3, csrc = (lane & 7) ^ rg;

    // XCD-aware decode: consecutive lin -> consecutive XCD (round-robin), so
    // give XCD x the groups 4x..4x+3; all 16 pair-blocks of a group share K/V.
    const int lin  = blockIdx.x;            // 0..511
    const int xcd  = lin & 7, sub = lin >> 3;
    const int grp  = xcd * 4 + (sub >> 4);  // 0..31 = (b,h)
    const int pair = sub & 15;
    const int h = grp & 15, b = grp >> 4;
    const float scale = 0.03125f;  // 1024^-0.5

    const size_t hb  = ((size_t)b * H_ + h) * T_ * HS_;   // q,k: [B,H,T,64]
    const u16* qh = q  + hb;
    const u16* kh = k  + hb;
    const u16* vh = vt + hb;                              // v: [B,H,64,T]

    auto stage = [&](int kv, int buf) {
        #pragma unroll
        for (int i = 0; i < 2; ++i) {
            const int seg = i * 4 + w;   // 0..7, wave-uniform
            gload_lds16(kh + (size_t)(kv * 64 + seg * 8 + rg) * 64 + csrc * 8,
                        &Kl[buf][seg * 512]);
            gload_lds16(vh + (size_t)(seg * 8 + rg) * T_ + kv * 64 + csrc * 8,
                        &Vl[buf][seg * 512]);
        }
    };

    int cur = 0;
    #pragma unroll
    for (int phase = 0; phase < 2; ++phase) {
        const int qt = phase ? (31 - pair) : pair;

        // Q fragments (A-frag: row = lane&15, k = g*8+reg)
        const size_t qrow_l = (size_t)(qt * 64 + w * 16 + c16);
        u16x8 qf[2];
        qf[0] = *(const u16x8*)&qh[qrow_l * 64 + g * 8];
        qf[1] = *(const u16x8*)&qh[qrow_l * 64 + 32 + g * 8];

        float m_run[4], l_run[4];
        f32x4 oacc[4];
        #pragma unroll
        for (int r = 0; r < 4; ++r) { m_run[r] = -INFINITY; l_run[r] = 0.f; }
        #pragma unroll
        for (int nt = 0; nt < 4; ++nt) oacc[nt] = f32x4{0.f, 0.f, 0.f, 0.f};

        __syncthreads();          // all waves done with prior phase's buffers
        stage(0, cur);            // prologue stage

        for (int kv = 0; kv <= qt; ++kv) {
            __syncthreads();      // tile kv ready (drains vmcnt); prev compute done
            if (kv < qt) stage(kv + 1, cur ^ 1);   // prefetch hides under compute

            // S = Q K^T  (4 key-tiles of 16)
            f32x4 s[4];
            #pragma unroll
            for (int kt = 0; kt < 4; ++kt) s[kt] = f32x4{0.f, 0.f, 0.f, 0.f};
            __builtin_amdgcn_s_setprio(1);
            #pragma unroll
            for (int kt = 0; kt < 4; ++kt)
                #pragma unroll
                for (int kk = 0; kk < 2; ++kk) {
                    const int row = kt * 16 + c16;
                    const int ch  = (kk * 4 + g) ^ (row & 7);
                    u16x8 kf = *(const u16x8*)&Kl[cur][row * 64 + ch * 8];
                    s[kt] = mfma_bf16(qf[kk], kf, s[kt]);
                }
            __builtin_amdgcn_s_setprio(0);

            // scale + causal mask (only diagonal tile)
            const bool last = (kv == qt);
            float sv[4][4];
            #pragma unroll
            for (int kt = 0; kt < 4; ++kt)
                #pragma unroll
                for (int r = 0; r < 4; ++r) {
                    float val = s[kt][r] * scale;
                    if (last && (kv * 64 + kt * 16 + c16) > (qt * 64 + w * 16 + g * 4 + r))
                        val = -INFINITY;
                    sv[kt][r] = val;
                }

            // row max across the 16 lanes holding each row
            float pm[4];
            #pragma unroll
            for (int r = 0; r < 4; ++r)
                pm[r] = fmaxf(fmaxf(sv[0][r], sv[1][r]), fmaxf(sv[2][r], sv[3][r]));
            #pragma unroll
            for (int mask = 1; mask < 16; mask <<= 1)
                #pragma unroll
                for (int r = 0; r < 4; ++r)
                    pm[r] = fmaxf(pm[r], __shfl_xor(pm[r], mask));

            float corr[4];
            #pragma unroll
            for (int r = 0; r < 4; ++r) {
                const float nm = fmaxf(m_run[r], pm[r]);
                corr[r] = __expf(m_run[r] - nm);   // 0 on first tile
                m_run[r] = nm;
            }

            float rs[4] = {0.f, 0.f, 0.f, 0.f};
            float ps[4][4];
            #pragma unroll
            for (int kt = 0; kt < 4; ++kt)
                #pragma unroll
                for (int r = 0; r < 4; ++r) {
                    const float p = __expf(sv[kt][r] - m_run[r]);
                    ps[kt][r] = p;
                    rs[r] += p;
                }
            #pragma unroll
            for (int mask = 1; mask < 16; mask <<= 1)
                #pragma unroll
                for (int r = 0; r < 4; ++r)
                    rs[r] += __shfl_xor(rs[r], mask);
            #pragma unroll
            for (int r = 0; r < 4; ++r) l_run[r] = l_run[r] * corr[r] + rs[r];
            #pragma unroll
            for (int nt = 0; nt < 4; ++nt)
                #pragma unroll
                for (int r = 0; r < 4; ++r) oacc[nt][r] *= corr[r];

            #pragma unroll
            for (int kt = 0; kt < 4; ++kt)
                #pragma unroll
                for (int r = 0; r < 4; ++r)
                    Pl[w * 1152 + (g * 4 + r) * 72 + kt * 16 + c16] = f2bf(ps[kt][r]);

            // O += P V
            __builtin_amdgcn_s_setprio(1);
            #pragma unroll
            for (int kkp = 0; kkp < 2; ++kkp) {
                u16x8 pf = *(const u16x8*)&Pl[w * 1152 + c16 * 72 + kkp * 32 + g * 8];
                #pragma unroll
                for (int nt = 0; nt < 4; ++nt) {
                    const int row = nt * 16 + c16;          // d
                    const int ch  = (kkp * 4 + g) ^ (row & 7);
                    u16x8 vf = *(const u16x8*)&Vl[cur][row * 64 + ch * 8];
                    oacc[nt] = mfma_bf16(pf, vf, oacc[nt]);
                }
            }
            __builtin_amdgcn_s_setprio(0);
            cur ^= 1;
        }

        // epilogue: o[b, t, h*64+d] bf16 in [M, C] layout
        float inv[4];
        #pragma unroll
        for (int r = 0; r < 4; ++r) inv[r] = 1.f / l_run[r];
        const int orow = qt * 64 + w * 16;
        #pragma unroll
        for (int nt = 0; nt < 4; ++nt)
            #pragma unroll
            for (int r = 0; r < 4; ++r)
                o[((size_t)(b * T_ + orow + g * 4 + r)) * C_ + h * 64 + nt * 16 + c16] =
                    f2bf(oacc[nt][r] * inv[r]);
    }
}

// ---------------------------------------------------------------------------
// Orchestration. ws layout (u16 elems, 64 MiB total):
//   [0)        Wqkvt  [3072][1024]          3,145,728
//   [3145728)  Wpt    [1024][1024]          1,048,576
//   [4194304)  W1t    [4096][1024]          4,194,304
//   [8388608)  W2t    [1024][4096]          4,194,304
//   [12582912) xb     [4096][1024]          4,194,304   (reused as x1b)
//   [16777216) q/k/vt 3x[B,H,..]           12,582,912   (reused as h1b)
//   [29360128) ab     [4096][1024]          4,194,304
// ---------------------------------------------------------------------------
extern "C" void kernel_launch(void* const* d_in, const int* in_sizes, int n_in,
                              void* d_out, int out_size, void* d_ws, size_t ws_size,
                              hipStream_t stream) {
    const float* x     = (const float*)d_in[0];
    const float* Wq    = (const float*)d_in[1];
    const float* Wk    = (const float*)d_in[2];
    const float* Wv    = (const float*)d_in[3];
    const float* Wproj = (const float*)d_in[4];
    const float* bproj = (const float*)d_in[5];
    const float* W1    = (const float*)d_in[6];
    const float* b1    = (const float*)d_in[7];
    const float* W2    = (const float*)d_in[8];
    const float* b2    = (const float*)d_in[9];
    float* out = (float*)d_out;

    u16* ws    = (u16*)d_ws;
    u16* Wqkvt = ws;
    u16* Wpt   = ws + 3145728;
    u16* W1t   = ws + 4194304;
    u16* W2t   = ws + 8388608;
    u16* xb    = ws + 12582912;
    u16* qb    = ws + 16777216;
    u16* ab    = ws + 29360128;
    u16* x1b   = xb;   // xb dead after QKV gemm
    u16* h1b   = qb;   // q/k/v + ab dead after proj gemm

    dim3 blk(256);

    cast_f32_bf16<<<dim3(2048), blk, 0, stream>>>(x, xb);
    transpose4_cast<<<dim3(16, 16, 4), blk, 0, stream>>>(Wq, Wk, Wv, Wproj, Wqkvt);
    transpose_cast<<<dim3(64, 16), blk, 0, stream>>>(W1, W1t, 1024, 4096);
    transpose_cast<<<dim3(16, 64), blk, 0, stream>>>(W2, W2t, 4096, 1024);

    // q/k -> [B,H,T,64], v -> [B,H,64,T] (transposed)
    gemm_bf16<EP_QKV, false, 128><<<dim3(24, 32), blk, 0, stream>>>(
        xb, Wqkvt, nullptr, nullptr, nullptr, qb, 3072, 1024);

    // causal flash attention (load-balanced pairs, XCD-aware) -> ab [M,C] bf16
    attn_mfma<<<dim3(512), blk, 0, stream>>>(
        qb, qb + 4194304, qb + 8388608, ab);

    // x1 = x + attn @ Wproj + bproj   (128x64 tile -> 512 blocks, 2/CU)
    gemm_bf16<EP_PROJ, true, 64><<<dim3(16, 32), blk, 0, stream>>>(
        ab, Wpt, bproj, x, out, x1b, 1024, 1024);

    // h1 = relu(x1 @ W1 + b1)
    gemm_bf16<EP_RELU, false, 128><<<dim3(32, 32), blk, 0, stream>>>(
        x1b, W1t, b1, nullptr, nullptr, h1b, 4096, 1024);

    // out = x1 + h1 @ W2 + b2         (128x64 tile -> 512 blocks, 2/CU)
    gemm_bf16<EP_RESID, true, 64><<<dim3(16, 32), blk, 0, stream>>>(
        h1b, W2t, b2, nullptr, out, nullptr, 1024, 4096);
}